// Round 3
// baseline (396.208 us; speedup 1.0000x reference)
//
#include <hip/hip_runtime.h>

// VectorQuantizer on MI355X (gfx950).
// k0  prep: split embedding f32->f16 hi/lo, code norms, zero accums
// kp  presplit z: [B,D,T] f32 -> zh/zl [N=B*T][D] f16 row-major (LDS transpose)
// k1p MFMA argmin GEMM (presplit path), padded LDS (stride 5 slots -> 2-way banks)
// k1  fallback MFMA argmin GEMM (in-kernel split) if ws too small
// k2  cross-chunk top-2 merge + ambiguity list (proxy gap < THRESH)
// k2b exact fp32 rescore (reference formula) over 16 candidates/row
// k3  gather + losses + histogram (float4), k4 finalize

typedef _Float16 f16;
typedef _Float16 f16x8 __attribute__((ext_vector_type(8)));
typedef float f32x4 __attribute__((ext_vector_type(4)));

#define NROWS 65536
#define THRESH 0.02f
#define AMB_CAP 32768

// merge (ov1,oi1,ov2,oi2) into (v1,i1,v2,i2); lowest-index tie-break like jnp.argmin
#define MERGE_T2(v1, i1, v2, i2, ov1, oi1, ov2, oi2)                      \
  do {                                                                    \
    if (ov1 < v1 || (ov1 == v1 && oi1 < i1)) {                            \
      if (v1 < ov2 || (v1 == ov2 && i1 < oi2)) { v2 = v1; i2 = i1; }      \
      else { v2 = ov2; i2 = oi2; }                                        \
      v1 = ov1; i1 = oi1;                                                 \
    } else if (ov1 < v2 || (ov1 == v2 && oi1 < i2)) { v2 = ov1; i2 = oi1; } \
  } while (0)

// ---------------- k0: split embedding, code norms, zero accumulators ----------------
__global__ void k0_prep(const float* __restrict__ emb, f16* __restrict__ eh,
                        f16* __restrict__ el, float* __restrict__ enorm,
                        float* __restrict__ counts, float* __restrict__ loss,
                        int* __restrict__ ambc) {
  int c = blockIdx.x, d = threadIdx.x;
  float v = emb[c * 256 + d];
  f16 h = (f16)v;
  f16 l = (f16)(v - (float)h);
  eh[c * 256 + d] = h;
  el[c * 256 + d] = l;
  float s = v * v;
#pragma unroll
  for (int o = 32; o; o >>= 1) s += __shfl_down(s, o, 64);
  __shared__ float red[4];
  if ((d & 63) == 0) red[d >> 6] = s;
  __syncthreads();
  if (d == 0) enorm[c] = red[0] + red[1] + red[2] + red[3];
  if (c == 0) {
    for (int i = d; i < 1024; i += 256) counts[i] = 0.f;
    if (d == 0) { *loss = 0.f; *ambc = 0; }
  }
}

// ---------------- kp: transpose+split z -> zh/zl [n][256] f16 ----------------
__global__ void kp_split(const float* __restrict__ z, f16* __restrict__ zh,
                         f16* __restrict__ zl) {
  __shared__ float F[64][65];
  int bid = blockIdx.x;
  int b = bid >> 7;
  int rem = bid & 127;
  int t0 = (rem >> 2) << 6;
  int dd0 = (rem & 3) << 6;
  int tid = threadIdx.x;
  int tl = tid & 63, dr = tid >> 6;
  const float* zp = z + ((size_t)b * 256 + dd0 + dr) * 2048 + t0 + tl;
#pragma unroll
  for (int i = 0; i < 16; ++i)
    F[dr + i * 4][tl] = zp[(size_t)i * 4 * 2048];  // coalesced over tl
  __syncthreads();
  int r = tid >> 2, q = tid & 3;  // r: t-local 0..63, q: d-quarter (16 d each)
  f16x8 h0, h1, l0, l1;
#pragma unroll
  for (int j = 0; j < 8; ++j) {
    float v = F[q * 16 + j][r];
    f16 h = (f16)v; h0[j] = h; l0[j] = (f16)(v - (float)h);
  }
#pragma unroll
  for (int j = 0; j < 8; ++j) {
    float v = F[q * 16 + 8 + j][r];
    f16 h = (f16)v; h1[j] = h; l1[j] = (f16)(v - (float)h);
  }
  size_t n = (size_t)b * 2048 + t0 + r;
  f16* ph = zh + n * 256 + dd0 + q * 16;
  f16* pl = zl + n * 256 + dd0 + q * 16;
  *(f16x8*)(ph) = h0; *(f16x8*)(ph + 8) = h1;
  *(f16x8*)(pl) = l0; *(f16x8*)(pl + 8) = l1;
}

// epilogue shared by k1p/k1: per-row top-2 with indices, cross-half merge, store
__device__ __forceinline__ void k1_epilogue(
    f32x4 (&acc)[4][4], const float* en_s, float* rv1, int* ri1, float* rv2, int* ri2,
    int tid, int wr, int wc, int g, int r16, int rowTile, int chunk, int cBase,
    float* cv1, int* ci1, float* cv2, int* ci2) {
  float en[4];
#pragma unroll
  for (int ni = 0; ni < 4; ++ni) en[ni] = en_s[wc * 64 + ni * 16 + r16];
#pragma unroll
  for (int mi = 0; mi < 4; ++mi) {
#pragma unroll
    for (int r = 0; r < 4; ++r) {
      float v1 = 1e38f, v2 = 1e38f; int i1 = 0x7fffffff, i2 = 0x7fffffff;
#pragma unroll
      for (int ni = 0; ni < 4; ++ni) {
        float v = en[ni] - 2.0f * acc[mi][ni][r];
        int idx = cBase + wc * 64 + ni * 16 + r16;
        if (v < v1 || (v == v1 && idx < i1)) { v2 = v1; i2 = i1; v1 = v; i1 = idx; }
        else if (v < v2 || (v == v2 && idx < i2)) { v2 = v; i2 = idx; }
      }
#pragma unroll
      for (int o = 1; o < 16; o <<= 1) {
        float ov1 = __shfl_xor(v1, o, 64); int oi1 = __shfl_xor(i1, o, 64);
        float ov2 = __shfl_xor(v2, o, 64); int oi2 = __shfl_xor(i2, o, 64);
        MERGE_T2(v1, i1, v2, i2, ov1, oi1, ov2, oi2);
      }
      if (r16 == 0) {
        int row = wr * 64 + mi * 16 + g * 4 + r;
        rv1[row * 2 + wc] = v1; ri1[row * 2 + wc] = i1;
        rv2[row * 2 + wc] = v2; ri2[row * 2 + wc] = i2;
      }
    }
  }
  __syncthreads();
  if (tid < 128) {
    float v1 = rv1[tid * 2], ov1 = rv1[tid * 2 + 1];
    int   i1 = ri1[tid * 2], oi1 = ri1[tid * 2 + 1];
    float v2 = rv2[tid * 2], ov2 = rv2[tid * 2 + 1];
    int   i2 = ri2[tid * 2], oi2 = ri2[tid * 2 + 1];
    MERGE_T2(v1, i1, v2, i2, ov1, oi1, ov2, oi2);
    size_t n = (size_t)rowTile * 128 + tid;
    cv1[(size_t)chunk * NROWS + n] = v1;
    ci1[(size_t)chunk * NROWS + n] = i1;
    cv2[(size_t)chunk * NROWS + n] = v2;
    ci2[(size_t)chunk * NROWS + n] = i2;
  }
}

// ---------------- k1p: 128x128 tile, K=256, split-f16 MFMA, presplit inputs ----------------
// LDS row stride = 5 f16x8 slots (80B): (row*5+slot)%8 cycles all bank-quads -> 2-way (free)
__launch_bounds__(256, 2)
__global__ void k1p_argmin(const f16* __restrict__ zh, const f16* __restrict__ zl,
                           const f16* __restrict__ eh, const f16* __restrict__ el,
                           const float* __restrict__ enorm,
                           float* __restrict__ cv1, int* __restrict__ ci1,
                           float* __restrict__ cv2, int* __restrict__ ci2) {
  __shared__ f16x8 Ah[128 * 5], Al[128 * 5], Bh[128 * 5], Bl[128 * 5];
  __shared__ float en_s[128];
  __shared__ float rv1[256], rv2[256];
  __shared__ int ri1[256], ri2[256];

  int bid = blockIdx.x;
  int x = bid & 7, j = bid >> 3;        // 8 chunk-sharers 8-apart -> same XCD
  int rowTile = x * 64 + (j >> 3);
  int chunk = j & 7;
  int n0 = rowTile * 128;
  int cBase = chunk << 7;

  int tid = threadIdx.x;
  int lane = tid & 63;
  int wid = tid >> 6;
  int wr = wid >> 1, wc = wid & 1;
  int g = lane >> 4, r16 = lane & 15;

  if (tid < 128) en_s[tid] = enorm[cBase + tid];

  f32x4 acc[4][4] = {};

  int tt = tid & 127;
  int kk2 = tid >> 7;
  const f16* zhb = zh + ((size_t)(n0 + tt)) * 256 + kk2 * 16;
  const f16* zlb = zl + ((size_t)(n0 + tt)) * 256 + kk2 * 16;
  const f16* ehb = eh + ((size_t)(cBase + tt)) * 256 + kk2 * 16;
  const f16* elb = el + ((size_t)(cBase + tt)) * 256 + kk2 * 16;
  int s0 = tt * 5 + kk2 * 2, s1 = s0 + 1;

  for (int ks = 0; ks < 8; ++ks) {
    if (ks) __syncthreads();
    Ah[s0] = *(const f16x8*)(zhb + ks * 32);
    Ah[s1] = *(const f16x8*)(zhb + ks * 32 + 8);
    Al[s0] = *(const f16x8*)(zlb + ks * 32);
    Al[s1] = *(const f16x8*)(zlb + ks * 32 + 8);
    Bh[s0] = *(const f16x8*)(ehb + ks * 32);
    Bh[s1] = *(const f16x8*)(ehb + ks * 32 + 8);
    Bl[s0] = *(const f16x8*)(elb + ks * 32);
    Bl[s1] = *(const f16x8*)(elb + ks * 32 + 8);
    __syncthreads();
    f16x8 ah[4], al[4], bh[4], bl[4];
#pragma unroll
    for (int mi = 0; mi < 4; ++mi) {
      int row = wr * 64 + mi * 16 + r16;
      ah[mi] = Ah[row * 5 + g];
      al[mi] = Al[row * 5 + g];
    }
#pragma unroll
    for (int ni = 0; ni < 4; ++ni) {
      int code = wc * 64 + ni * 16 + r16;
      bh[ni] = Bh[code * 5 + g];
      bl[ni] = Bl[code * 5 + g];
    }
#pragma unroll
    for (int mi = 0; mi < 4; ++mi)
#pragma unroll
      for (int ni = 0; ni < 4; ++ni) {
        acc[mi][ni] = __builtin_amdgcn_mfma_f32_16x16x32_f16(ah[mi], bh[ni], acc[mi][ni], 0, 0, 0);
        acc[mi][ni] = __builtin_amdgcn_mfma_f32_16x16x32_f16(ah[mi], bl[ni], acc[mi][ni], 0, 0, 0);
        acc[mi][ni] = __builtin_amdgcn_mfma_f32_16x16x32_f16(al[mi], bh[ni], acc[mi][ni], 0, 0, 0);
      }
  }
  k1_epilogue(acc, en_s, rv1, ri1, rv2, ri2, tid, wr, wc, g, r16, rowTile, chunk,
              cBase, cv1, ci1, cv2, ci2);
}

// ---------------- k1: fallback (in-kernel split), used when ws too small ----------------
__launch_bounds__(256, 2)
__global__ void k1_argmin(const float* __restrict__ z, const f16* __restrict__ eh,
                          const f16* __restrict__ el, const float* __restrict__ enorm,
                          float* __restrict__ cv1, int* __restrict__ ci1,
                          float* __restrict__ cv2, int* __restrict__ ci2) {
  __shared__ f16x8 Ah[128 * 5], Al[128 * 5], Bh[128 * 5], Bl[128 * 5];
  __shared__ float en_s[128];
  __shared__ float rv1[256], rv2[256];
  __shared__ int ri1[256], ri2[256];

  int bid = blockIdx.x;
  int x = bid & 7, j = bid >> 3;
  int rowTile = x * 64 + (j >> 3);
  int chunk = j & 7;
  int bb = rowTile >> 4;
  int t0 = (rowTile & 15) << 7;
  int cBase = chunk << 7;

  int tid = threadIdx.x;
  int lane = tid & 63;
  int wid = tid >> 6;
  int wr = wid >> 1, wc = wid & 1;
  int g = lane >> 4, r16 = lane & 15;

  if (tid < 128) en_s[tid] = enorm[cBase + tid];

  f32x4 acc[4][4] = {};

  int tt = tid & 127;
  int kk2 = tid >> 7;
  const float* zbase = z + ((size_t)bb * 256 + kk2 * 16) * 2048 + t0 + tt;
  const f16* ehbase = eh + ((size_t)(cBase + tt)) * 256 + kk2 * 16;
  const f16* elbase = el + ((size_t)(cBase + tt)) * 256 + kk2 * 16;
  int s0 = tt * 5 + kk2 * 2, s1 = s0 + 1;

  for (int ks = 0; ks < 8; ++ks) {
    if (ks) __syncthreads();
    {
      const float* zp = zbase + (size_t)ks * 32 * 2048;
      f16x8 h8, l8;
#pragma unroll
      for (int cj = 0; cj < 8; ++cj) {
        float v = zp[cj * 2048];
        f16 h = (f16)v; h8[cj] = h; l8[cj] = (f16)(v - (float)h);
      }
      Ah[s0] = h8; Al[s0] = l8;
#pragma unroll
      for (int cj = 0; cj < 8; ++cj) {
        float v = zp[(8 + cj) * 2048];
        f16 h = (f16)v; h8[cj] = h; l8[cj] = (f16)(v - (float)h);
      }
      Ah[s1] = h8; Al[s1] = l8;
    }
    {
      const f16* ep = ehbase + ks * 32;
      Bh[s0] = *(const f16x8*)(ep);
      Bh[s1] = *(const f16x8*)(ep + 8);
      const f16* ep2 = elbase + ks * 32;
      Bl[s0] = *(const f16x8*)(ep2);
      Bl[s1] = *(const f16x8*)(ep2 + 8);
    }
    __syncthreads();
    f16x8 ah[4], al[4], bh[4], bl[4];
#pragma unroll
    for (int mi = 0; mi < 4; ++mi) {
      int row = wr * 64 + mi * 16 + r16;
      ah[mi] = Ah[row * 5 + g];
      al[mi] = Al[row * 5 + g];
    }
#pragma unroll
    for (int ni = 0; ni < 4; ++ni) {
      int code = wc * 64 + ni * 16 + r16;
      bh[ni] = Bh[code * 5 + g];
      bl[ni] = Bl[code * 5 + g];
    }
#pragma unroll
    for (int mi = 0; mi < 4; ++mi)
#pragma unroll
      for (int ni = 0; ni < 4; ++ni) {
        acc[mi][ni] = __builtin_amdgcn_mfma_f32_16x16x32_f16(ah[mi], bh[ni], acc[mi][ni], 0, 0, 0);
        acc[mi][ni] = __builtin_amdgcn_mfma_f32_16x16x32_f16(ah[mi], bl[ni], acc[mi][ni], 0, 0, 0);
        acc[mi][ni] = __builtin_amdgcn_mfma_f32_16x16x32_f16(al[mi], bh[ni], acc[mi][ni], 0, 0, 0);
      }
  }
  k1_epilogue(acc, en_s, rv1, ri1, rv2, ri2, tid, wr, wc, g, r16, rowTile, chunk,
              cBase, cv1, ci1, cv2, ci2);
}

// ---------------- k2: cross-chunk merge + ambiguity detection ----------------
__global__ void k2_select(const float* __restrict__ cv1, const int* __restrict__ ci1,
                          const float* __restrict__ cv2, const int* __restrict__ ci2,
                          int* __restrict__ fidx, int* __restrict__ ambc,
                          int* __restrict__ amb_list) {
  int n = blockIdx.x * 256 + threadIdx.x;
  float g1 = 1e38f, g2 = 1e38f; int gi1 = 0x7fffffff, gi2 = 0x7fffffff;
#pragma unroll
  for (int c = 0; c < 8; ++c) {
    float ov1 = cv1[c * NROWS + n]; int oi1 = ci1[c * NROWS + n];
    float ov2 = cv2[c * NROWS + n]; int oi2 = ci2[c * NROWS + n];
    MERGE_T2(g1, gi1, g2, gi2, ov1, oi1, ov2, oi2);
  }
  fidx[n] = gi1;
  if (g2 - g1 < THRESH) {
    int pos = atomicAdd(ambc, 1);
    if (pos < AMB_CAP) amb_list[pos] = n;
  }
}

// ---------------- k2b: exact fp32 rescore (reference formula), 16 candidates ----------------
__global__ void k2b_rescore(const float* __restrict__ z, const float* __restrict__ emb,
                            const float* __restrict__ enorm,
                            const int* __restrict__ ci1, const int* __restrict__ ci2,
                            const int* __restrict__ ambc, const int* __restrict__ amb_list,
                            int* __restrict__ fidx) {
  int cnt = *ambc; if (cnt > AMB_CAP) cnt = AMB_CAP;
  int lane = threadIdx.x & 63;
  int wglobal = (blockIdx.x * 256 + threadIdx.x) >> 6;
  for (int a = wglobal; a < cnt; a += 256) {
    int n = amb_list[a];
    int bb = n >> 11, t = n & 2047;
    float zr[4];
#pragma unroll
    for (int jj = 0; jj < 4; ++jj)
      zr[jj] = z[((size_t)bb * 256 + lane * 4 + jj) * 2048 + t];
    float zn = zr[0] * zr[0] + zr[1] * zr[1] + zr[2] * zr[2] + zr[3] * zr[3];
#pragma unroll
    for (int o = 1; o < 64; o <<= 1) zn += __shfl_xor(zn, o, 64);
    float bv = 1e38f; int bi = 0x7fffffff;
    for (int cc = 0; cc < 16; ++cc) {
      int c = cc >> 1;
      int cand = (cc & 1) ? ci2[c * NROWS + n] : ci1[c * NROWS + n];
      const float4* e4p = (const float4*)(emb + (size_t)cand * 256);
      float4 e4 = e4p[lane];
      float s = zr[0] * e4.x + zr[1] * e4.y + zr[2] * e4.z + zr[3] * e4.w;
#pragma unroll
      for (int o = 1; o < 64; o <<= 1) s += __shfl_xor(s, o, 64);
      float d = zn + enorm[cand] - 2.0f * s;   // reference formula, fp32
      if (d < bv || (d == bv && cand < bi)) { bv = d; bi = cand; }
    }
    if (lane == 0) fidx[n] = bi;
  }
}

// ---------------- k3: gather codebook rows, write out [B,D,T], loss, histogram ----------------
__global__ void k3_gather(const float* __restrict__ z, const float* __restrict__ emb,
                          const int* __restrict__ fidx, float* __restrict__ out,
                          float* __restrict__ counts, float* __restrict__ loss) {
  __shared__ int sidx[128];
  __shared__ float red[4];
  int rowTile = blockIdx.x;
  int bb = rowTile >> 4;
  int t0 = (rowTile & 15) << 7;
  int tid = threadIdx.x;
  if (tid < 128) sidx[tid] = fidx[rowTile * 128 + tid];
  __syncthreads();
  int q = tid & 31, dh = (tid >> 5) << 5;  // 32 t-quads x 8 d-slices of 32
  const float* e0 = emb + (size_t)sidx[q * 4 + 0] * 256;
  const float* e1 = emb + (size_t)sidx[q * 4 + 1] * 256;
  const float* e2 = emb + (size_t)sidx[q * 4 + 2] * 256;
  const float* e3 = emb + (size_t)sidx[q * 4 + 3] * 256;
  size_t zb = ((size_t)bb * 256 + dh) * 2048 + t0 + q * 4;
  float ls = 0.f;
  for (int i = 0; i < 32; ++i) {
    int d = dh + i;
    float4 z4 = *(const float4*)(z + zb + (size_t)i * 2048);
    float4 e4 = make_float4(e0[d], e1[d], e2[d], e3[d]);  // L2-resident gather
    *(float4*)(out + zb + (size_t)i * 2048) = e4;
    float da = e4.x - z4.x, db = e4.y - z4.y, dc = e4.z - z4.z, dd = e4.w - z4.w;
    ls += da * da + db * db + dc * dc + dd * dd;
  }
#pragma unroll
  for (int o = 32; o; o >>= 1) ls += __shfl_down(ls, o, 64);
  if ((tid & 63) == 0) red[tid >> 6] = ls;
  __syncthreads();
  if (tid == 0) atomicAdd(loss, red[0] + red[1] + red[2] + red[3]);
  if (tid < 128) atomicAdd(counts + sidx[tid], 1.0f);
}

// ---------------- k4: losses + perplexity ----------------
__global__ void k4_final(const float* __restrict__ counts, const float* __restrict__ loss,
                         float* __restrict__ outs) {
  __shared__ float red[4];
  int tid = threadIdx.x;
  float h = 0.f;
  for (int i = tid; i < 1024; i += 256) {
    float p = counts[i] * (1.0f / 65536.0f);
    h += p * logf(p + 1e-10f);
  }
#pragma unroll
  for (int o = 32; o; o >>= 1) h += __shfl_down(h, o, 64);
  if ((tid & 63) == 0) red[tid >> 6] = h;
  __syncthreads();
  if (tid == 0) {
    float H = red[0] + red[1] + red[2] + red[3];
    float perp = expf(-H);
    float l = *loss * (1.0f / 16777216.0f);
    outs[0] = l;   // z_qut_loss
    outs[1] = l;   // z_enc_loss (numerically identical)
    outs[2] = perp;
  }
}

extern "C" void kernel_launch(void* const* d_in, const int* in_sizes, int n_in,
                              void* d_out, int out_size, void* d_ws, size_t ws_size,
                              hipStream_t stream) {
  const float* z = (const float*)d_in[0];     // [32,256,2048]
  const float* emb = (const float*)d_in[1];   // [1024,256]
  float* out = (float*)d_out;                 // 16777216 + 3
  char* ws = (char*)d_ws;
  f16*   eh     = (f16*)(ws);                          // 512 KiB
  f16*   el     = (f16*)(ws + (512u << 10));           // 512 KiB
  float* enorm  = (float*)(ws + (1u << 20));           // 4 KiB
  float* counts = (float*)(ws + (1u << 20) + 4096);    // 4 KiB
  float* lossp  = (float*)(ws + (1u << 20) + 8192);
  int*   ambc   = (int*)  (ws + (1u << 20) + 8196);
  int*   amb_l  = (int*)  (ws + (1u << 20) + 16384);   // 128 KiB
  float* cv1    = (float*)(ws + (2u << 20));           // 2 MiB
  int*   ci1    = (int*)  (ws + (4u << 20));           // 2 MiB
  float* cv2    = (float*)(ws + (6u << 20));           // 2 MiB
  int*   ci2    = (int*)  (ws + (8u << 20));           // 2 MiB
  int*   fidx   = (int*)  (ws + (10u << 20));          // 256 KiB
  f16*   zh     = (f16*)(ws + (11u << 20));            // 32 MiB
  f16*   zl     = (f16*)(ws + (43u << 20));            // 32 MiB
  const size_t NEED_PRESPLIT = 75u << 20;

  hipLaunchKernelGGL(k0_prep, dim3(1024), dim3(256), 0, stream, emb, eh, el, enorm, counts, lossp, ambc);
  if (ws_size >= NEED_PRESPLIT) {
    hipLaunchKernelGGL(kp_split,   dim3(4096), dim3(256), 0, stream, z, zh, zl);
    hipLaunchKernelGGL(k1p_argmin, dim3(4096), dim3(256), 0, stream, zh, zl, eh, el, enorm, cv1, ci1, cv2, ci2);
  } else {
    hipLaunchKernelGGL(k1_argmin,  dim3(4096), dim3(256), 0, stream, z, eh, el, enorm, cv1, ci1, cv2, ci2);
  }
  hipLaunchKernelGGL(k2_select,   dim3(256), dim3(256), 0, stream, cv1, ci1, cv2, ci2, fidx, ambc, amb_l);
  hipLaunchKernelGGL(k2b_rescore, dim3(64),  dim3(256), 0, stream, z, emb, enorm, ci1, ci2, ambc, amb_l, fidx);
  hipLaunchKernelGGL(k3_gather,   dim3(512), dim3(256), 0, stream, z, emb, fidx, out, counts, lossp);
  hipLaunchKernelGGL(k4_final,    dim3(1),   dim3(256), 0, stream, counts, lossp, out + 16777216);
}

// Round 5
// 360.273 us; speedup vs baseline: 1.0997x; 1.0997x over previous
//
#include <hip/hip_runtime.h>

// VectorQuantizer on MI355X (gfx950).
// k0  prep: split embedding f32->f16 hi/lo into K-TILED layout, code norms, zero accums
// kp  presplit z: [B,D,T] f32 -> zh/zl in K-TILED layout [rt][ks][g][row][8] f16
// k1p MFMA argmin GEMM: global_load_lds(16B) staging, linear LDS, conflict-free frags
// k2  cross-chunk top-2 merge + ambiguity list (proxy gap < THRESH)
// k2b exact fp32 rescore (reference formula) over 16 candidates/row
// k3  gather + losses + histogram (float4), k4 finalize

typedef _Float16 f16;
typedef _Float16 f16x8 __attribute__((ext_vector_type(8)));
typedef float f32x4 __attribute__((ext_vector_type(4)));

#define NROWS 65536
#define THRESH 0.02f
#define AMB_CAP 32768

#define MERGE_T2(v1, i1, v2, i2, ov1, oi1, ov2, oi2)                      \
  do {                                                                    \
    if (ov1 < v1 || (ov1 == v1 && oi1 < i1)) {                            \
      if (v1 < ov2 || (v1 == ov2 && i1 < oi2)) { v2 = v1; i2 = i1; }      \
      else { v2 = ov2; i2 = oi2; }                                        \
      v1 = ov1; i1 = oi1;                                                 \
    } else if (ov1 < v2 || (ov1 == v2 && oi1 < i2)) { v2 = ov1; i2 = oi1; } \
  } while (0)

// async global->LDS, 16B per lane; lds base must be wave-uniform
__device__ __forceinline__ void gl16(const void* g, void* l) {
  __builtin_amdgcn_global_load_lds(
      (const __attribute__((address_space(1))) unsigned int*)g,
      (__attribute__((address_space(3))) unsigned int*)l, 16, 0, 0);
}

// ---------------- k0: split embedding into tiled layout + norms + zero accums ----------------
__global__ void k0_prep(const float* __restrict__ emb, f16* __restrict__ eh,
                        f16* __restrict__ el, float* __restrict__ enorm,
                        float* __restrict__ counts, float* __restrict__ loss,
                        int* __restrict__ ambc) {
  int c = blockIdx.x, d = threadIdx.x;
  float v = emb[c * 256 + d];
  f16 h = (f16)v;
  f16 l = (f16)(v - (float)h);
  // tiled: [chunk][ks][g][crow][8]
  int chunk = c >> 7, crow = c & 127;
  int ks = d >> 5, gg = (d >> 3) & 3, e = d & 7;
  size_t off = ((((size_t)chunk * 8 + ks) * 4 + gg) * 128 + crow) * 8 + e;
  eh[off] = h;
  el[off] = l;
  float s = v * v;
#pragma unroll
  for (int o = 32; o; o >>= 1) s += __shfl_down(s, o, 64);
  __shared__ float red[4];
  if ((d & 63) == 0) red[d >> 6] = s;
  __syncthreads();
  if (d == 0) enorm[c] = red[0] + red[1] + red[2] + red[3];
  if (c == 0) {
    for (int i = d; i < 1024; i += 256) counts[i] = 0.f;
    if (d == 0) { *loss = 0.f; *ambc = 0; }
  }
}

// ---------------- kp: transpose+split z -> zh/zl tiled [rt][ks][g][row][8] ----------------
__global__ void kp_split(const float* __restrict__ z, f16* __restrict__ zh,
                         f16* __restrict__ zl) {
  __shared__ float F[64][65];
  int bid = blockIdx.x;
  int b = bid >> 7;
  int rem = bid & 127;
  int t0 = (rem >> 2) << 6;
  int dd0 = (rem & 3) << 6;
  int tid = threadIdx.x;
  int tl = tid & 63, dr = tid >> 6;
  const float* zp = z + ((size_t)b * 256 + dd0 + dr) * 2048 + t0 + tl;
#pragma unroll
  for (int i = 0; i < 16; ++i)
    F[dr + i * 4][tl] = zp[(size_t)i * 4 * 2048];  // coalesced over tl
  __syncthreads();
  int r = tid >> 2, q = tid & 3;  // r: t-local 0..63, q: 16-d group
  f16x8 h0, h1, l0, l1;
#pragma unroll
  for (int j = 0; j < 8; ++j) {
    float v = F[q * 16 + j][r];
    f16 h = (f16)v; h0[j] = h; l0[j] = (f16)(v - (float)h);
  }
#pragma unroll
  for (int j = 0; j < 8; ++j) {
    float v = F[q * 16 + 8 + j][r];
    f16 h = (f16)v; h1[j] = h; l1[j] = (f16)(v - (float)h);
  }
  int n = b * 2048 + t0 + r;
  int rt = n >> 7, row = n & 127;
  int d0 = dd0 + q * 16;
  int ks = d0 >> 5, g0 = (d0 >> 3) & 3;
  size_t base = ((((size_t)rt * 8 + ks) * 4 + g0) * 128 + row) * 8;
  *(f16x8*)(zh + base) = h0; *(f16x8*)(zh + base + 1024) = h1;
  *(f16x8*)(zl + base) = l0; *(f16x8*)(zl + base + 1024) = l1;
}

// ---------------- k1p: 128x128 tile, K=256, split-f16 MFMA, global_load_lds staging --------
__launch_bounds__(256, 3)
__global__ void k1p_argmin(const f16* __restrict__ zh, const f16* __restrict__ zl,
                           const f16* __restrict__ eh, const f16* __restrict__ el,
                           const float* __restrict__ enorm,
                           float* __restrict__ cv1, int* __restrict__ ci1,
                           float* __restrict__ cv2, int* __restrict__ ci2) {
  __shared__ f16x8 Ah[512], Al[512], Bh[512], Bl[512];  // [g 0..3][row 0..127]
  __shared__ float en_s[128];
  __shared__ float rv1[256], rv2[256];
  __shared__ int ri1[256], ri2[256];

  int bid = blockIdx.x;
  int x = bid & 7, j = bid >> 3;        // 8 chunk-sharers 8-apart -> same XCD
  int rowTile = x * 64 + (j >> 3);
  int chunk = j & 7;
  int cBase = chunk << 7;

  int tid = threadIdx.x;
  int lane = tid & 63;
  int w = tid >> 6;
  int wr = w >> 1, wc = w & 1;
  int g = lane >> 4, r16 = lane & 15;

  if (tid < 128) en_s[tid] = enorm[cBase + tid];

  f32x4 acc[4][4] = {};

  // per-wave source/dest bases; per (tile,ks) block = 8KB contiguous
  const char* gAh = (const char*)zh + (size_t)rowTile * 65536 + w * 2048 + lane * 16;
  const char* gAl = (const char*)zl + (size_t)rowTile * 65536 + w * 2048 + lane * 16;
  const char* gBh = (const char*)eh + (size_t)chunk * 65536 + w * 2048 + lane * 16;
  const char* gBl = (const char*)el + (size_t)chunk * 65536 + w * 2048 + lane * 16;
  char* lAh = (char*)Ah + w * 2048;
  char* lAl = (char*)Al + w * 2048;
  char* lBh = (char*)Bh + w * 2048;
  char* lBl = (char*)Bl + w * 2048;

  for (int ks = 0; ks < 8; ++ks) {
    if (ks) __syncthreads();
    size_t go = (size_t)ks * 8192;
    gl16(gAh + go, lAh);  gl16(gAh + go + 1024, lAh + 1024);
    gl16(gAl + go, lAl);  gl16(gAl + go + 1024, lAl + 1024);
    gl16(gBh + go, lBh);  gl16(gBh + go + 1024, lBh + 1024);
    gl16(gBl + go, lBl);  gl16(gBl + go + 1024, lBl + 1024);
    __syncthreads();
    f16x8 bh[4], bl[4];
#pragma unroll
    for (int ni = 0; ni < 4; ++ni) {
      int code = wc * 64 + ni * 16 + r16;
      bh[ni] = Bh[g * 128 + code];
      bl[ni] = Bl[g * 128 + code];
    }
#pragma unroll
    for (int mi = 0; mi < 4; ++mi) {
      int row = wr * 64 + mi * 16 + r16;
      f16x8 ah = Ah[g * 128 + row];
      f16x8 al = Al[g * 128 + row];
#pragma unroll
      for (int ni = 0; ni < 4; ++ni) {
        acc[mi][ni] = __builtin_amdgcn_mfma_f32_16x16x32_f16(ah, bh[ni], acc[mi][ni], 0, 0, 0);
        acc[mi][ni] = __builtin_amdgcn_mfma_f32_16x16x32_f16(ah, bl[ni], acc[mi][ni], 0, 0, 0);
        acc[mi][ni] = __builtin_amdgcn_mfma_f32_16x16x32_f16(al, bh[ni], acc[mi][ni], 0, 0, 0);
      }
    }
  }
  // epilogue: proxy dist, per-row top-2 with indices, cross-half merge, store
  float en[4];
#pragma unroll
  for (int ni = 0; ni < 4; ++ni) en[ni] = en_s[wc * 64 + ni * 16 + r16];
#pragma unroll
  for (int mi = 0; mi < 4; ++mi) {
#pragma unroll
    for (int r = 0; r < 4; ++r) {
      float v1 = 1e38f, v2 = 1e38f; int i1 = 0x7fffffff, i2 = 0x7fffffff;
#pragma unroll
      for (int ni = 0; ni < 4; ++ni) {
        float v = en[ni] - 2.0f * acc[mi][ni][r];
        int idx = cBase + wc * 64 + ni * 16 + r16;
        if (v < v1 || (v == v1 && idx < i1)) { v2 = v1; i2 = i1; v1 = v; i1 = idx; }
        else if (v < v2 || (v == v2 && idx < i2)) { v2 = v; i2 = idx; }
      }
#pragma unroll
      for (int o = 1; o < 16; o <<= 1) {
        float ov1 = __shfl_xor(v1, o, 64); int oi1 = __shfl_xor(i1, o, 64);
        float ov2 = __shfl_xor(v2, o, 64); int oi2 = __shfl_xor(i2, o, 64);
        MERGE_T2(v1, i1, v2, i2, ov1, oi1, ov2, oi2);
      }
      if (r16 == 0) {
        int row = wr * 64 + mi * 16 + g * 4 + r;
        rv1[row * 2 + wc] = v1; ri1[row * 2 + wc] = i1;
        rv2[row * 2 + wc] = v2; ri2[row * 2 + wc] = i2;
      }
    }
  }
  __syncthreads();
  if (tid < 128) {
    float v1 = rv1[tid * 2], ov1 = rv1[tid * 2 + 1];
    int   i1 = ri1[tid * 2], oi1 = ri1[tid * 2 + 1];
    float v2 = rv2[tid * 2], ov2 = rv2[tid * 2 + 1];
    int   i2 = ri2[tid * 2], oi2 = ri2[tid * 2 + 1];
    MERGE_T2(v1, i1, v2, i2, ov1, oi1, ov2, oi2);
    size_t n = (size_t)rowTile * 128 + tid;
    cv1[(size_t)chunk * NROWS + n] = v1;
    ci1[(size_t)chunk * NROWS + n] = i1;
    cv2[(size_t)chunk * NROWS + n] = v2;
    ci2[(size_t)chunk * NROWS + n] = i2;
  }
}

// ---------------- k2: cross-chunk merge + ambiguity detection ----------------
__global__ void k2_select(const float* __restrict__ cv1, const int* __restrict__ ci1,
                          const float* __restrict__ cv2, const int* __restrict__ ci2,
                          int* __restrict__ fidx, int* __restrict__ ambc,
                          int* __restrict__ amb_list) {
  int n = blockIdx.x * 256 + threadIdx.x;
  float g1 = 1e38f, g2 = 1e38f; int gi1 = 0x7fffffff, gi2 = 0x7fffffff;
#pragma unroll
  for (int c = 0; c < 8; ++c) {
    float ov1 = cv1[c * NROWS + n]; int oi1 = ci1[c * NROWS + n];
    float ov2 = cv2[c * NROWS + n]; int oi2 = ci2[c * NROWS + n];
    MERGE_T2(g1, gi1, g2, gi2, ov1, oi1, ov2, oi2);
  }
  fidx[n] = gi1;
  if (g2 - g1 < THRESH) {
    int pos = atomicAdd(ambc, 1);
    if (pos < AMB_CAP) amb_list[pos] = n;
  }
}

// ---------------- k2b: exact fp32 rescore (reference formula), 16 candidates ----------------
__global__ void k2b_rescore(const float* __restrict__ z, const float* __restrict__ emb,
                            const float* __restrict__ enorm,
                            const int* __restrict__ ci1, const int* __restrict__ ci2,
                            const int* __restrict__ ambc, const int* __restrict__ amb_list,
                            int* __restrict__ fidx) {
  int cnt = *ambc; if (cnt > AMB_CAP) cnt = AMB_CAP;
  int lane = threadIdx.x & 63;
  int wglobal = (blockIdx.x * 256 + threadIdx.x) >> 6;
  for (int a = wglobal; a < cnt; a += 256) {
    int n = amb_list[a];
    int bb = n >> 11, t = n & 2047;
    float zr[4];
#pragma unroll
    for (int jj = 0; jj < 4; ++jj)
      zr[jj] = z[((size_t)bb * 256 + lane * 4 + jj) * 2048 + t];
    float zn = zr[0] * zr[0] + zr[1] * zr[1] + zr[2] * zr[2] + zr[3] * zr[3];
#pragma unroll
    for (int o = 1; o < 64; o <<= 1) zn += __shfl_xor(zn, o, 64);
    float bv = 1e38f; int bi = 0x7fffffff;
    for (int cc = 0; cc < 16; ++cc) {
      int c = cc >> 1;
      int cand = (cc & 1) ? ci2[c * NROWS + n] : ci1[c * NROWS + n];
      const float4* e4p = (const float4*)(emb + (size_t)cand * 256);
      float4 e4 = e4p[lane];
      float s = zr[0] * e4.x + zr[1] * e4.y + zr[2] * e4.z + zr[3] * e4.w;
#pragma unroll
      for (int o = 1; o < 64; o <<= 1) s += __shfl_xor(s, o, 64);
      float d = zn + enorm[cand] - 2.0f * s;   // reference formula, fp32
      if (d < bv || (d == bv && cand < bi)) { bv = d; bi = cand; }
    }
    if (lane == 0) fidx[n] = bi;
  }
}

// ---------------- k3: gather codebook rows, write out [B,D,T], loss, histogram ----------------
__global__ void k3_gather(const float* __restrict__ z, const float* __restrict__ emb,
                          const int* __restrict__ fidx, float* __restrict__ out,
                          float* __restrict__ counts, float* __restrict__ loss) {
  __shared__ int sidx[128];
  __shared__ float red[4];
  int rowTile = blockIdx.x;
  int bb = rowTile >> 4;
  int t0 = (rowTile & 15) << 7;
  int tid = threadIdx.x;
  if (tid < 128) sidx[tid] = fidx[rowTile * 128 + tid];
  __syncthreads();
  int q = tid & 31, dh = (tid >> 5) << 5;  // 32 t-quads x 8 d-slices of 32
  const float* e0 = emb + (size_t)sidx[q * 4 + 0] * 256;
  const float* e1 = emb + (size_t)sidx[q * 4 + 1] * 256;
  const float* e2 = emb + (size_t)sidx[q * 4 + 2] * 256;
  const float* e3 = emb + (size_t)sidx[q * 4 + 3] * 256;
  size_t zb = ((size_t)bb * 256 + dh) * 2048 + t0 + q * 4;
  float ls = 0.f;
  for (int i = 0; i < 32; ++i) {
    int d = dh + i;
    float4 z4 = *(const float4*)(z + zb + (size_t)i * 2048);
    float4 e4 = make_float4(e0[d], e1[d], e2[d], e3[d]);  // L2-resident gather
    *(float4*)(out + zb + (size_t)i * 2048) = e4;
    float da = e4.x - z4.x, db = e4.y - z4.y, dc = e4.z - z4.z, dd = e4.w - z4.w;
    ls += da * da + db * db + dc * dc + dd * dd;
  }
#pragma unroll
  for (int o = 32; o; o >>= 1) ls += __shfl_down(ls, o, 64);
  if ((tid & 63) == 0) red[tid >> 6] = ls;
  __syncthreads();
  if (tid == 0) atomicAdd(loss, red[0] + red[1] + red[2] + red[3]);
  if (tid < 128) atomicAdd(counts + sidx[tid], 1.0f);
}

// ---------------- k4: losses + perplexity ----------------
__global__ void k4_final(const float* __restrict__ counts, const float* __restrict__ loss,
                         float* __restrict__ outs) {
  __shared__ float red[4];
  int tid = threadIdx.x;
  float h = 0.f;
  for (int i = tid; i < 1024; i += 256) {
    float p = counts[i] * (1.0f / 65536.0f);
    h += p * logf(p + 1e-10f);
  }
#pragma unroll
  for (int o = 32; o; o >>= 1) h += __shfl_down(h, o, 64);
  if ((tid & 63) == 0) red[tid >> 6] = h;
  __syncthreads();
  if (tid == 0) {
    float H = red[0] + red[1] + red[2] + red[3];
    float perp = expf(-H);
    float l = *loss * (1.0f / 16777216.0f);
    outs[0] = l;   // z_qut_loss
    outs[1] = l;   // z_enc_loss (numerically identical)
    outs[2] = perp;
  }
}

extern "C" void kernel_launch(void* const* d_in, const int* in_sizes, int n_in,
                              void* d_out, int out_size, void* d_ws, size_t ws_size,
                              hipStream_t stream) {
  const float* z = (const float*)d_in[0];     // [32,256,2048]
  const float* emb = (const float*)d_in[1];   // [1024,256]
  float* out = (float*)d_out;                 // 16777216 + 3
  char* ws = (char*)d_ws;
  f16*   eh     = (f16*)(ws);                          // 512 KiB (tiled)
  f16*   el     = (f16*)(ws + (512u << 10));           // 512 KiB (tiled)
  float* enorm  = (float*)(ws + (1u << 20));           // 4 KiB
  float* counts = (float*)(ws + (1u << 20) + 4096);    // 4 KiB
  float* lossp  = (float*)(ws + (1u << 20) + 8192);
  int*   ambc   = (int*)  (ws + (1u << 20) + 8196);
  int*   amb_l  = (int*)  (ws + (1u << 20) + 16384);   // 128 KiB
  float* cv1    = (float*)(ws + (2u << 20));           // 2 MiB
  int*   ci1    = (int*)  (ws + (4u << 20));           // 2 MiB
  float* cv2    = (float*)(ws + (6u << 20));           // 2 MiB
  int*   ci2    = (int*)  (ws + (8u << 20));           // 2 MiB
  int*   fidx   = (int*)  (ws + (10u << 20));          // 256 KiB
  f16*   zh     = (f16*)(ws + (11u << 20));            // 32 MiB (tiled)
  f16*   zl     = (f16*)(ws + (43u << 20));            // 32 MiB (tiled)

  hipLaunchKernelGGL(k0_prep,     dim3(1024), dim3(256), 0, stream, emb, eh, el, enorm, counts, lossp, ambc);
  hipLaunchKernelGGL(kp_split,    dim3(4096), dim3(256), 0, stream, z, zh, zl);
  hipLaunchKernelGGL(k1p_argmin,  dim3(4096), dim3(256), 0, stream, zh, zl, eh, el, enorm, cv1, ci1, cv2, ci2);
  hipLaunchKernelGGL(k2_select,   dim3(256), dim3(256), 0, stream, cv1, ci1, cv2, ci2, fidx, ambc, amb_l);
  hipLaunchKernelGGL(k2b_rescore, dim3(64),  dim3(256), 0, stream, z, emb, enorm, ci1, ci2, ambc, amb_l, fidx);
  hipLaunchKernelGGL(k3_gather,   dim3(512), dim3(256), 0, stream, z, emb, fidx, out, counts, lossp);
  hipLaunchKernelGGL(k4_final,    dim3(1),   dim3(256), 0, stream, counts, lossp, out + 16777216);
}